// Round 2
// baseline (1799.410 us; speedup 1.0000x reference)
//
#include <hip/hip_runtime.h>
#include <stdint.h>

#define TT 1024
#define HB 256
#define BB 256
#define CAP 48                      // per half-row entry capacity (mean ~12.8)
#define O1 67108864u                // B*T*H
#define O2 (67108864u + 524288u)    // + B*T*2

__device__ __forceinline__ uint32_t rotl32(uint32_t x, uint32_t r){ return (x<<r)|(x>>(32u-r)); }

// Threefry-2x32, 20 rounds, generalized key
__device__ __forceinline__ void tf2x32(uint32_t k0, uint32_t k1, uint32_t& x0, uint32_t& x1){
  const uint32_t ks2 = 0x1BD11BDAu ^ k0 ^ k1;
  x0 += k0; x1 += k1;
#define RND(r) { x0+=x1; x1=rotl32(x1,(r)); x1^=x0; }
  RND(13) RND(15) RND(26) RND(6)  x0+=k1;  x1+=ks2+1u;
  RND(17) RND(29) RND(16) RND(24) x0+=ks2; x1+=k0+2u;
  RND(13) RND(15) RND(26) RND(6)  x0+=k0;  x1+=k1+3u;
  RND(17) RND(29) RND(16) RND(24) x0+=k1;  x1+=ks2+4u;
  RND(13) RND(15) RND(26) RND(6)  x0+=ks2; x1+=k0+5u;
#undef RND
}

// XLA ErfInv f32 (Giles polynomial) — matches jax.lax.erf_inv expansion
__device__ __forceinline__ float erfinv_f(float x){
  float w = -log1pf(-x*x);
  float p;
  if (w < 5.0f){
    w -= 2.5f;
    p = 2.81022636e-08f;
    p = fmaf(p, w, 3.43273939e-07f);
    p = fmaf(p, w, -3.5233877e-06f);
    p = fmaf(p, w, -4.39150654e-06f);
    p = fmaf(p, w, 0.00021858087f);
    p = fmaf(p, w, -0.00125372503f);
    p = fmaf(p, w, -0.00417768164f);
    p = fmaf(p, w, 0.246640727f);
    p = fmaf(p, w, 1.50140941f);
  } else {
    w = sqrtf(w) - 3.0f;
    p = -0.000200214257f;
    p = fmaf(p, w, 0.000100950558f);
    p = fmaf(p, w, 0.00134934322f);
    p = fmaf(p, w, -0.00367342844f);
    p = fmaf(p, w, 0.00573950773f);
    p = fmaf(p, w, -0.0076224613f);
    p = fmaf(p, w, 0.00943887047f);
    p = fmaf(p, w, 1.00167406f);
    p = fmaf(p, w, 2.83297682f);
  }
  return p * x;
}

// JAX uniform(lo=nextafter(-1,0), hi=1) -> sqrt(2)*erfinv -> *0.05*0.5
__device__ __forceinline__ float bits_to_noise(uint32_t bits){
  float f = __uint_as_float((bits>>9) | 0x3F800000u) - 1.0f;   // [0,1)
  const float lo = -0.99999994f;
  float u = fmaxf(fmaf(f, 1.99999994f, lo), lo);               // exact f32 (hi-lo)
  float r = 1.41421356237f * erfinv_f(u);
  return (r * 0.05f) * 0.5f;
}

__global__ void init_flags(uint32_t* flags){
  if (flags) { flags[0]=0u; flags[1]=0u; flags[2]=0u; flags[3]=0u; }
}

// Partitionable threefry: per flat index i (uint64, here <2^32):
// (o0,o1)=tf(key,(0,i)); bits = o0^o1. Noise for (t,b,j) -> hidden_list[b,t,j].
__global__ void noise_kernel(float* __restrict__ out, uint32_t* __restrict__ flags){
  uint32_t i = blockIdx.x*256u + threadIdx.x;   // 0 .. 2^26-1
  uint32_t x0 = 0u, x1 = i;
  tf2x32(0u, 42u, x0, x1);
  float n = bits_to_noise(x0 ^ x1);
  if (flags && (!(fabsf(n) <= 0.2f))) flags[1] = 1u;   // NaN or out-of-range
  uint32_t t = i >> 16, b = (i >> 8) & 255u, j = i & 255u;
  out[(uint64_t)(b*TT + t)*HB + j] = n;
}

// Self-test: known Random123/JAX threefry vectors + erfinv anchors.
__global__ void check_kernel(float* out, const uint32_t* flags){
  uint32_t a0=0u, a1=0u;                 tf2x32(0u,0u,a0,a1);
  uint32_t b0=0xffffffffu, b1=0xffffffffu; tf2x32(0xffffffffu,0xffffffffu,b0,b1);
  uint32_t c0=0x243f6a88u, c1=0x85a308d3u; tf2x32(0x13198a2eu,0x03707344u,c0,c1);
  if (!(a0==0x6b200159u && a1==0x99ba4efeu)) out[0] = 1e30f;
  if (!(b0==0x1cb996fcu && b1==0xbb002be7u)) out[1] = 2e30f;
  if (!(c0==0xc4923a9cu && c1==0x483df7a0u)) out[2] = 3e30f;
  if (!(fabsf(erfinv_f(0.5f)   - 0.47693628f) < 1e-4f)) out[3] = 4e30f;
  if (!(fabsf(erfinv_f(0.999f) - 2.3267538f)  < 2e-3f)) out[4] = 5e30f;
  if (flags && flags[0]) out[5] = 6e30f;   // CAP overflow
  if (flags && flags[1]) out[6] = 7e30f;   // noise sanity
}

__launch_bounds__(512, 1)
__global__ void rnn_kernel(const float* __restrict__ input_signal, // [B,T,2]
                           const float* __restrict__ hidden0,      // [B,H]
                           const float* __restrict__ w_in,         // [H,2]
                           const float* __restrict__ w_out,        // [2,H]
                           const float* __restrict__ abs_w0,       // [H,H]
                           const float* __restrict__ w_sign,       // [H,H]
                           const float* __restrict__ is_con,       // [H,H]
                           float* __restrict__ out,
                           uint32_t* __restrict__ flags)
{
  __shared__ uint32_t ent[2*CAP*HB];     // [slot][row], transposed: conflict-free
  __shared__ float tbuf[2][HB];          // double-buffered tanh(h)
  __shared__ float partials[2][16];

  const int tid  = threadIdx.x;
  const int j    = tid >> 1;
  const int half = tid & 1;
  const int lane = tid & 63;
  const int wv   = tid >> 6;
  const int b    = blockIdx.x;

  int cnt = 0, tot = 0;
  {
    const int base  = j*HB + half*128;
    const int sbase = half*CAP;
    for (int k = 0; k < 128; ++k){
      float c = is_con[base + k];
      float w = w_sign[base + k] * abs_w0[base + k];
      if (c > 0.0f){
        ++tot;
        if (cnt < CAP){
          uint32_t e = (__float_as_uint(w) + 0x80u) & 0xFFFFFF00u;
          e |= (uint32_t)(half*128 + k);
          ent[(sbase + cnt)*HB + j] = e;
          ++cnt;
        }
      }
    }
  }
  if (flags && tot > CAP) flags[0] = 1u;

  const float wi0 = w_in[j*2 + 0], wi1 = w_in[j*2 + 1];
  const float wo  = (half == 0) ? w_out[j] : w_out[HB + j];
  float h = hidden0[b*HB + j];
  const float* xin  = input_signal + (uint64_t)b*TT*2;
  float*       hrow = out + (uint64_t)b*TT*HB;
  float*       orow = out + O1 + (uint64_t)b*TT*2;
  const int sbase = half*CAP;

  __syncthreads();

  for (int t = 0; t < TT; ++t){
    const int buf = t & 1;
    float th = 1.0f - 2.0f/(__expf(2.0f*h) + 1.0f);   // tanh
    tbuf[buf][j] = th;
    float nz = hrow[t*HB + j];
    float x0 = xin[t*2 + 0], x1 = xin[t*2 + 1];
    __syncthreads();

    if (t > 0 && tid < 2){
      float o = 0.0f;
      #pragma unroll
      for (int w2 = 0; w2 < 8; ++w2) o += partials[1 - buf][w2*2 + tid];
      orow[(t-1)*2 + tid] = o;
    }

    float y = 0.0f;
    const float* tb = tbuf[buf];
    for (int i = 0; i < cnt; ++i){
      uint32_t e = ent[(sbase + i)*HB + j];
      float wgt  = __uint_as_float(e & 0xFFFFFF00u);
      y = fmaf(wgt, tb[e & 0xFFu], y);
    }
    y += __shfl_xor(y, 1, 64);

    float u = fmaf(x0, wi0, x1*wi1);
    h = fmaf(0.25f, u + y, 0.75f*h) + nz;

    if (half == 0) hrow[t*HB + j] = h;

    float p = h * wo;
    p += __shfl_xor(p, 2, 64);
    p += __shfl_xor(p, 4, 64);
    p += __shfl_xor(p, 8, 64);
    p += __shfl_xor(p, 16, 64);
    p += __shfl_xor(p, 32, 64);
    if (lane < 2) partials[buf][wv*2 + lane] = p;
  }

  __syncthreads();
  if (tid < 2){
    float o = 0.0f;
    #pragma unroll
    for (int w2 = 0; w2 < 8; ++w2) o += partials[1][w2*2 + tid];
    orow[(TT-1)*2 + tid] = o;
  }
  if (half == 0) out[O2 + b*HB + j] = h;
}

extern "C" void kernel_launch(void* const* d_in, const int* in_sizes, int n_in,
                              void* d_out, int out_size, void* d_ws, size_t ws_size,
                              hipStream_t stream) {
  const float* input_signal = (const float*)d_in[0];
  const float* hidden       = (const float*)d_in[1];
  const float* w_in         = (const float*)d_in[2];
  const float* w_out        = (const float*)d_in[3];
  const float* abs_w0       = (const float*)d_in[4];
  const float* w_sign       = (const float*)d_in[5];
  const float* is_con       = (const float*)d_in[6];
  float* out = (float*)d_out;
  uint32_t* flags = (ws_size >= 16) ? (uint32_t*)d_ws : nullptr;

  init_flags<<<1, 1, 0, stream>>>(flags);
  noise_kernel<<<262144, 256, 0, stream>>>(out, flags);
  rnn_kernel<<<BB, 512, 0, stream>>>(input_signal, hidden, w_in, w_out,
                                     abs_w0, w_sign, is_con, out, flags);
  check_kernel<<<1, 1, 0, stream>>>(out, flags);
}

// Round 3
// 1319.627 us; speedup vs baseline: 1.3636x; 1.3636x over previous
//
#include <hip/hip_runtime.h>
#include <stdint.h>

#define TT 1024
#define HB 256
#define BB 256
#define NITER 24                    // per-lane entry slots (covers row total <= 48)
#define O1 67108864u                // B*T*H
#define O2 (67108864u + 524288u)    // + B*T*2

__device__ __forceinline__ uint32_t rotl32(uint32_t x, uint32_t r){ return (x<<r)|(x>>(32u-r)); }

// Threefry-2x32, 20 rounds
__device__ __forceinline__ void tf2x32(uint32_t k0, uint32_t k1, uint32_t& x0, uint32_t& x1){
  const uint32_t ks2 = 0x1BD11BDAu ^ k0 ^ k1;
  x0 += k0; x1 += k1;
#define RND(r) { x0+=x1; x1=rotl32(x1,(r)); x1^=x0; }
  RND(13) RND(15) RND(26) RND(6)  x0+=k1;  x1+=ks2+1u;
  RND(17) RND(29) RND(16) RND(24) x0+=ks2; x1+=k0+2u;
  RND(13) RND(15) RND(26) RND(6)  x0+=k0;  x1+=k1+3u;
  RND(17) RND(29) RND(16) RND(24) x0+=k1;  x1+=ks2+4u;
  RND(13) RND(15) RND(26) RND(6)  x0+=ks2; x1+=k0+5u;
#undef RND
}

__device__ __forceinline__ float erfinv_f(float x){
  float w = -log1pf(-x*x);
  float p;
  if (w < 5.0f){
    w -= 2.5f;
    p = 2.81022636e-08f;
    p = fmaf(p, w, 3.43273939e-07f);
    p = fmaf(p, w, -3.5233877e-06f);
    p = fmaf(p, w, -4.39150654e-06f);
    p = fmaf(p, w, 0.00021858087f);
    p = fmaf(p, w, -0.00125372503f);
    p = fmaf(p, w, -0.00417768164f);
    p = fmaf(p, w, 0.246640727f);
    p = fmaf(p, w, 1.50140941f);
  } else {
    w = sqrtf(w) - 3.0f;
    p = -0.000200214257f;
    p = fmaf(p, w, 0.000100950558f);
    p = fmaf(p, w, 0.00134934322f);
    p = fmaf(p, w, -0.00367342844f);
    p = fmaf(p, w, 0.00573950773f);
    p = fmaf(p, w, -0.0076224613f);
    p = fmaf(p, w, 0.00943887047f);
    p = fmaf(p, w, 1.00167406f);
    p = fmaf(p, w, 2.83297682f);
  }
  return p * x;
}

__device__ __forceinline__ float bits_to_noise(uint32_t bits){
  float f = __uint_as_float((bits>>9) | 0x3F800000u) - 1.0f;
  const float lo = -0.99999994f;
  float u = fmaxf(fmaf(f, 1.99999994f, lo), lo);
  float r = 1.41421356237f * erfinv_f(u);
  return (r * 0.05f) * 0.5f;
}

__global__ void init_flags(uint32_t* flags){
  if (flags) { flags[0]=0u; flags[1]=0u; }
}

// Self-test: threefry vectors + erfinv anchors + overflow flag -> poison out
__global__ void check_kernel(float* out, const uint32_t* flags){
  uint32_t a0=0u, a1=0u;                 tf2x32(0u,0u,a0,a1);
  uint32_t b0=0xffffffffu, b1=0xffffffffu; tf2x32(0xffffffffu,0xffffffffu,b0,b1);
  uint32_t c0=0x243f6a88u, c1=0x85a308d3u; tf2x32(0x13198a2eu,0x03707344u,c0,c1);
  if (!(a0==0x6b200159u && a1==0x99ba4efeu)) out[0] = 1e30f;
  if (!(b0==0x1cb996fcu && b1==0xbb002be7u)) out[1] = 2e30f;
  if (!(c0==0xc4923a9cu && c1==0x483df7a0u)) out[2] = 3e30f;
  if (!(fabsf(erfinv_f(0.5f)   - 0.47693628f) < 1e-4f)) out[3] = 4e30f;
  if (!(fabsf(erfinv_f(0.999f) - 2.3267538f)  < 2e-3f)) out[4] = 5e30f;
  if (flags && flags[0]) out[5] = 6e30f;   // entry-slot overflow
}

__launch_bounds__(512, 1)
__global__ void rnn_kernel(const float* __restrict__ input_signal, // [B,T,2]
                           const float* __restrict__ hidden0,      // [B,H]
                           const float* __restrict__ w_in,         // [H,2]
                           const float* __restrict__ abs_w0,       // [H,H]
                           const float* __restrict__ w_sign,       // [H,H]
                           const float* __restrict__ is_con,       // [H,H]
                           float* __restrict__ out,
                           uint32_t* __restrict__ flags)
{
  __shared__ uint32_t ebuf[NITER*512];   // 48 KB: one-time bounce to registers
  __shared__ float tbuf[2][2][HB];       // [t-parity][lane-parity copy][j] 4 KB
  __shared__ float nbuf[3][HB];          // noise triple-buffer 3 KB

  const int tid  = threadIdx.x;
  const int j    = tid >> 1;
  const int half = tid & 1;
  const int b    = blockIdx.x;

  // ---- build balanced, padded entry list (bounce via LDS -> registers) ----
  {
    int seq = 0, mine = 0, skipped = 0;
    const int base = j*HB;
    for (int k = 0; k < HB; ++k){
      float c = is_con[base + k];
      if (c > 0.0f){
        if ((seq & 1) == half){
          int slot = seq >> 1;
          if (slot < NITER){
            float w = w_sign[base+k] * abs_w0[base+k];
            uint32_t e = (__float_as_uint(w) + 0x80u) & 0xFFFFFF00u; // weight, 16-bit-trunc mantissa
            ebuf[slot*512 + tid] = e | (uint32_t)k;                  // low 8 bits: source idx
            ++mine;
          } else skipped = 1;
        }
        ++seq;
      }
    }
    for (int s = mine; s < NITER; ++s)
      ebuf[s*512 + tid] = (uint32_t)j;    // weight +0.0, idx=j (spread dummy banks)
    if (flags && skipped) flags[0] = 1u;
  }
  __syncthreads();
  uint32_t e[NITER];
  #pragma unroll
  for (int s = 0; s < NITER; ++s) e[s] = ebuf[s*512 + tid];

  const float wi0 = w_in[j*2 + 0], wi1 = w_in[j*2 + 1];
  float h = hidden0[b*HB + j];
  const float* xin  = input_signal + (uint64_t)b*TT*2;
  float*       hrow = out + (uint64_t)b*TT*HB;

  // noise prologue: step 0 values
  if (tid < HB){
    uint32_t x0 = 0u, x1 = (uint32_t)b*256u + (uint32_t)tid;  // t=0 flat index
    tf2x32(0u, 42u, x0, x1);
    nbuf[0][tid] = bits_to_noise(x0 ^ x1);
  }

  for (int t = 0; t < TT; ++t){
    const int par = t & 1;
    float th = 1.0f - 2.0f/(__expf(2.0f*h) + 1.0f);   // tanh
    tbuf[par][half][j] = th;

    float nval = 0.0f;
    if (tid < HB){                                     // waves 0-3: gen noise for t+1
      uint32_t x0 = 0u, x1 = (uint32_t)(t+1)*65536u + (uint32_t)b*256u + (uint32_t)tid;
      tf2x32(0u, 42u, x0, x1);
      nval = bits_to_noise(x0 ^ x1);
    }
    float xx0 = xin[t*2 + 0], xx1 = xin[t*2 + 1];      // uniform -> scalar loads

    __syncthreads();                                   // the ONE barrier per step

    if (tid < HB) nbuf[(t+1)%3][tid] = nval;

    const float* tbp = &tbuf[par][half][0];
    float y = 0.0f;
    #pragma unroll
    for (int s = 0; s < NITER; ++s){
      uint32_t ee = e[s];
      y = fmaf(__uint_as_float(ee & 0xFFFFFF00u), tbp[ee & 0xFFu], y);
    }
    y += __shfl_xor(y, 1, 64);                         // combine pair halves

    float nz = nbuf[t%3][j];
    float u  = fmaf(xx0, wi0, xx1*wi1);
    h = fmaf(0.25f, u + y, 0.75f*h) + nz;

    if (half == 0) hrow[t*HB + j] = h;
  }
  if (half == 0) out[O2 + b*HB + j] = h;
}

// Post-pass: output projection from hidden_list (full parallelism)
__global__ void outproj_kernel(const float* __restrict__ w_out,  // [2,H]
                               float* __restrict__ out)
{
  const int lane = threadIdx.x & 63;
  const int wv   = threadIdx.x >> 6;
  const float4 w0 = *(const float4*)(w_out + lane*4);
  const float4 w1 = *(const float4*)(w_out + HB + lane*4);
  const int wrow = blockIdx.x*4 + wv;          // 0..8191
  const float* hb = out;

  for (int it = 0; it < 32; ++it){
    int r = wrow*32 + it;                      // r = b*T + t
    const float4 v = *(const float4*)(hb + (uint64_t)r*HB + lane*4);
    float p0 = v.x*w0.x + v.y*w0.y + v.z*w0.z + v.w*w0.w;
    float p1 = v.x*w1.x + v.y*w1.y + v.z*w1.z + v.w*w1.w;
    #pragma unroll
    for (int m = 1; m < 64; m <<= 1){
      p0 += __shfl_xor(p0, m, 64);
      p1 += __shfl_xor(p1, m, 64);
    }
    if (lane == 0) *(float2*)(out + O1 + (uint64_t)r*2) = make_float2(p0, p1);
  }
}

extern "C" void kernel_launch(void* const* d_in, const int* in_sizes, int n_in,
                              void* d_out, int out_size, void* d_ws, size_t ws_size,
                              hipStream_t stream) {
  const float* input_signal = (const float*)d_in[0];
  const float* hidden       = (const float*)d_in[1];
  const float* w_in         = (const float*)d_in[2];
  const float* w_out        = (const float*)d_in[3];
  const float* abs_w0       = (const float*)d_in[4];
  const float* w_sign       = (const float*)d_in[5];
  const float* is_con       = (const float*)d_in[6];
  float* out = (float*)d_out;
  uint32_t* flags = (ws_size >= 8) ? (uint32_t*)d_ws : nullptr;

  init_flags<<<1, 1, 0, stream>>>(flags);
  rnn_kernel<<<BB, 512, 0, stream>>>(input_signal, hidden, w_in,
                                     abs_w0, w_sign, is_con, out, flags);
  outproj_kernel<<<2048, 256, 0, stream>>>(w_out, out);
  check_kernel<<<1, 1, 0, stream>>>(out, flags);
}